// Round 12
// baseline (572.602 us; speedup 1.0000x reference)
//
#include <hip/hip_runtime.h>

#define NLAT 361
#define NLON 720
#define LMAX 360
#define MMAX 361

#define NS   6                        // n-split across blocks
#define QN   61                       // slice width: 6*61 = 366 >= 361
#define NN   64                       // padded main-loop iterations per slice
#define XTQ_FLOATS (MMAX * NLAT * 8)  // 1,042,568 per slice (real Xt [m][k][8ch])

#define DFT_REP 20
#define RED_REP 40
#define CON_REP 10

static constexpr float kAngF = 8.72664625997164788e-3f;  // 2*pi/720

// ---------------- kernel 1: folded real DFT, Chebyshev recurrence ----------------
__global__ __launch_bounds__(256) void k_dft4(const float* __restrict__ x,
                                              float* __restrict__ xtq, int rep) {
    const int bx  = blockIdx.x;      // k pair: k = 2*bx + ks
    const int nq  = blockIdx.y;      // n slice
    const int tid = threadIdx.x;
    const int ks  = tid >> 7;        // 0/1
    const int ml  = tid & 127;       // m lane
    const int n0  = nq * QN;

    __shared__ __align__(16) float xe[2][NN][8];

    int mm[3];
    mm[0] = ml; mm[1] = ml + 128;
    const bool m2v = (ml + 256 <= 360);
    mm[2] = m2v ? (ml + 256) : 360;
    const int k = bx * 2 + ks;

    for (int r = 0; r < rep; ++r) {
        asm volatile("" ::: "memory");   // forbid load hoist/CSE across reps

        // fold: xe[s][nn][ch] = x[n] + x[720-n]; zero outside this slice (nn<QN)
        for (int j = tid; j < 2 * 8 * NN; j += 256) {
            int s  = j / (8 * NN);
            int rr = j - s * (8 * NN);
            int ch = rr / NN;
            int nn = rr - ch * NN;
            int n  = n0 + nn;
            int kq = bx * 2 + s;
            float v = 0.f;
            if (nn < QN && n <= 360 && kq <= 360) {
                const float* __restrict__ row = x + ((size_t)ch * NLAT + kq) * NLON;
                float a = row[n];
                float b = (n == 0) ? 0.f : row[NLON - n];
                v = a + b;
            }
            xe[s][nn][ch] = v;
        }
        __syncthreads();

        float P0[3], P1[3], c2[3];
#pragma unroll
        for (int q = 0; q < 3; ++q) {
            int m  = mm[q];
            int t0 = (n0 * m) % NLON;
            int t1 = t0 + m; if (t1 >= NLON) t1 -= NLON;
            P0[q] = cosf((float)t0 * kAngF);
            P1[q] = cosf((float)t1 * kAngF);
            c2[q] = 2.f * cosf((float)m * kAngF);
        }

        float acc[3][8];
#pragma unroll
        for (int q = 0; q < 3; ++q)
#pragma unroll
            for (int b = 0; b < 8; ++b) acc[q][b] = 0.f;

#pragma unroll 4
        for (int nn = 0; nn < NN; ++nn) {
            float4 e0 = *(const float4*)&xe[ks][nn][0];
            float4 e1 = *(const float4*)&xe[ks][nn][4];
#pragma unroll
            for (int q = 0; q < 3; ++q) {
                float f = P0[q];
                acc[q][0] += f * e0.x;  acc[q][1] += f * e0.y;
                acc[q][2] += f * e0.z;  acc[q][3] += f * e0.w;
                acc[q][4] += f * e1.x;  acc[q][5] += f * e1.y;
                acc[q][6] += f * e1.z;  acc[q][7] += f * e1.w;
                float Pn = c2[q] * P1[q] - P0[q];
                P0[q] = P1[q];
                P1[q] = Pn;
            }
        }

        if (nq == NS - 1) {      // n=360 weight-0.5 fixup (sits at nn=55, slice 5)
            float4 e0 = *(const float4*)&xe[ks][55][0];
            float4 e1 = *(const float4*)&xe[ks][55][4];
#pragma unroll
            for (int q = 0; q < 3; ++q) {
                float sgn = (mm[q] & 1) ? -1.f : 1.f;
                float h = 0.5f * sgn;
                acc[q][0] -= h * e0.x;  acc[q][1] -= h * e0.y;
                acc[q][2] -= h * e0.z;  acc[q][3] -= h * e0.w;
                acc[q][4] -= h * e1.x;  acc[q][5] -= h * e1.y;
                acc[q][6] -= h * e1.z;  acc[q][7] -= h * e1.w;
            }
        }

#pragma unroll
        for (int q = 0; q < 3; ++q)
#pragma unroll
            for (int b = 0; b < 8; ++b) acc[q][b] *= kAngF;

        if (k <= 360) {
            float4* __restrict__ o4 = (float4*)(xtq + (size_t)nq * XTQ_FLOATS);
            int b0 = (mm[0] * NLAT + k) * 2;
            o4[b0]     = make_float4(acc[0][0], acc[0][1], acc[0][2], acc[0][3]);
            o4[b0 + 1] = make_float4(acc[0][4], acc[0][5], acc[0][6], acc[0][7]);
            int b1 = (mm[1] * NLAT + k) * 2;
            o4[b1]     = make_float4(acc[1][0], acc[1][1], acc[1][2], acc[1][3]);
            o4[b1 + 1] = make_float4(acc[1][4], acc[1][5], acc[1][6], acc[1][7]);
            if (m2v) {
                int b2 = (mm[2] * NLAT + k) * 2;
                o4[b2]     = make_float4(acc[2][0], acc[2][1], acc[2][2], acc[2][3]);
                o4[b2 + 1] = make_float4(acc[2][4], acc[2][5], acc[2][6], acc[2][7]);
            }
        }
        __syncthreads();         // xe reused next rep
    }
}

// ---------------- kernel 1b: sum the NS n-slices ----------------
__global__ __launch_bounds__(256) void k_reduce6(const float* __restrict__ q,
                                                 float4* __restrict__ o, int rep) {
    int i = blockIdx.x * 256 + threadIdx.x;
    if (i >= XTQ_FLOATS / 4) return;
    const float4* q4 = (const float4*)q;
    for (int r = 0; r < rep; ++r) {
        asm volatile("" ::: "memory");
        float4 s = q4[i];
#pragma unroll
        for (int u = 1; u < NS; ++u) {
            float4 a = q4[i + (size_t)u * (XTQ_FLOATS / 4)];
            s.x += a.x; s.y += a.y; s.z += a.z; s.w += a.w;
        }
        o[i] = s;
    }
}

// ---------------- kernel 2: contraction, all-W-upfront registers ----------------
__global__ __launch_bounds__(256) void k_contract4(const float* __restrict__ W,
                                                   const float* __restrict__ xt,
                                                   float* __restrict__ out, int rep) {
    const int lt   = blockIdx.x;
    const int mloc = blockIdx.y;
    const int m    = mloc;
    const int l0   = lt * 32;
    const int tid  = threadIdx.x;
    const int kk = tid & 31, lq = tid >> 5;
    const int lb = l0 + lq * 4;

    for (int r = 0; r < rep; ++r) {
        asm volatile("" ::: "memory");

        if (l0 + 31 < m) {
            int l = l0 + (tid >> 3), bc = tid & 7;
            out[(bc * LMAX + l) * MMAX + m] = 0.f;
            continue;
        }

        int lr[4];
#pragma unroll
        for (int j = 0; j < 4; ++j) {
            int l = lb + j;
            if (l < m)        l = m;
            if (l > LMAX - 1) l = LMAX - 1;
            lr[j] = l;
        }

        const float* __restrict__ Wm = W + (size_t)m * (LMAX * NLAT);
        const float* __restrict__ r0 = Wm + lr[0] * NLAT + kk;
        const float* __restrict__ r1 = Wm + lr[1] * NLAT + kk;
        const float* __restrict__ r2 = Wm + lr[2] * NLAT + kk;
        const float* __restrict__ r3 = Wm + lr[3] * NLAT + kk;

        float wv[12][4];
#pragma unroll
        for (int t = 0; t < 11; ++t) {
            wv[t][0] = r0[t * 32];
            wv[t][1] = r1[t * 32];
            wv[t][2] = r2[t * 32];
            wv[t][3] = r3[t * 32];
        }
        {
            int kq = 11 * 32 + kk;
            int kc = (kq <= 360) ? kq : 360;
            wv[11][0] = Wm[lr[0] * NLAT + kc];
            wv[11][1] = Wm[lr[1] * NLAT + kc];
            wv[11][2] = Wm[lr[2] * NLAT + kc];
            wv[11][3] = Wm[lr[3] * NLAT + kc];
            if (kq > 360) { wv[11][0] = wv[11][1] = wv[11][2] = wv[11][3] = 0.f; }
        }

        float v[32];
#pragma unroll
        for (int i = 0; i < 32; ++i) v[i] = 0.f;

        const float4* __restrict__ xt4 = (const float4*)xt;
#pragma unroll
        for (int t = 0; t < 12; ++t) {
            int kq = t * 32 + kk;
            int kc = (kq <= 360) ? kq : 360;
            int xb = (mloc * NLAT + kc) * 2;
            float4 x0 = xt4[xb], x1 = xt4[xb + 1];
#pragma unroll
            for (int j = 0; j < 4; ++j) {
                float wj = wv[t][j];
                v[j*8 + 0] += wj * x0.x;  v[j*8 + 1] += wj * x0.y;
                v[j*8 + 2] += wj * x0.z;  v[j*8 + 3] += wj * x0.w;
                v[j*8 + 4] += wj * x1.x;  v[j*8 + 5] += wj * x1.y;
                v[j*8 + 6] += wj * x1.z;  v[j*8 + 7] += wj * x1.w;
            }
        }

#define RSTEP(MASK, CNT) { const bool hi = (kk & MASK) != 0; \
    _Pragma("unroll") \
    for (int i = 0; i < CNT; ++i) { \
        float keep = hi ? v[i + CNT] : v[i]; \
        float send = hi ? v[i] : v[i + CNT]; \
        v[i] = keep + __shfl_xor(send, MASK); } }
        RSTEP(16, 16) RSTEP(8, 8) RSTEP(4, 4) RSTEP(2, 2) RSTEP(1, 1)
#undef RSTEP

        int j  = kk >> 3;
        int bc = kk & 7;
        int l  = l0 + lq * 4 + j;
        if (l < LMAX) {
            float rv = (l < m) ? 0.f : v[0];
            out[(bc * LMAX + l) * MMAX + m] = rv;
        }
    }
}

// ---------------- legacy folded DFT (cplx hedge / small-ws fallback) ----------------
template<int CPLX>
__global__ __launch_bounds__(192) void k_dft_leg(const float* __restrict__ x,
                                                 float* __restrict__ xt,
                                                 int mb, int mc) {
    const int k    = blockIdx.x;
    const int half = blockIdx.y;
    const int tid  = threadIdx.x;

    __shared__ __align__(16) float  xr[8 * 724];
    __shared__ __align__(16) float2 exo[8 * 362];

    {
        const float4* __restrict__ x4 = (const float4*)x;
        for (int j = tid; j < 8 * 180; j += 192) {
            int b = j / 180, q = j - b * 180;
            ((float4*)&xr[b * 724])[q] = x4[(b * NLAT + k) * 180 + q];
        }
        if (tid < 8) ((float4*)&xr[tid * 724])[180] = make_float4(0.f, 0.f, 0.f, 0.f);
    }
    __syncthreads();

    for (int j = tid; j < 8 * NLAT; j += 192) {
        int b = j / NLAT, n = j - b * NLAT;
        float xa  = xr[b * 724 + n];
        float xbv = xr[b * 724 + (NLON - n)];
        exo[b * 362 + n] = make_float2(xa + xbv, xa - xbv);
    }
    __syncthreads();

    const int  m_local = half * 192 + tid;
    const bool valid   = (m_local < mc);
    const int  m       = mb + (valid ? m_local : 0);

    float aRe[8], aIm[8];
#pragma unroll
    for (int b = 0; b < 8; ++b) { aRe[b] = 0.f; aIm[b] = 0.f; }

    int tacc = 0;
    for (int n = 0; n < NLAT; ++n) {
        float sn, cs;
        __sincosf((float)tacc * kAngF, &sn, &cs);
        float wgt = (n == 360) ? 0.5f : 1.0f;
        float fc = wgt * kAngF * cs;
        float fs = -wgt * kAngF * sn;
        tacc += m;
        if (tacc >= NLON) tacc -= NLON;
#pragma unroll
        for (int b = 0; b < 8; ++b) {
            float2 e = exo[b * 362 + n];
            aRe[b] += fc * e.x;
            if (CPLX) aIm[b] += fs * e.y;
        }
    }

    if (valid) {
        float4* __restrict__ xt4 = (float4*)xt;
        if (CPLX) {
            int base = (m_local * NLAT + k) * 4;
#pragma unroll
            for (int q = 0; q < 4; ++q)
                xt4[base + q] = make_float4(aRe[2*q], aIm[2*q], aRe[2*q+1], aIm[2*q+1]);
        } else {
            int base = (m_local * NLAT + k) * 2;
            xt4[base + 0] = make_float4(aRe[0], aRe[1], aRe[2], aRe[3]);
            xt4[base + 1] = make_float4(aRe[4], aRe[5], aRe[6], aRe[7]);
        }
    }
}

// ---------------- legacy contraction (fallback only) ----------------
template<int CPLX>
__global__ __launch_bounds__(256) void k_contract_leg(const float* __restrict__ W,
                                                      const float* __restrict__ xt,
                                                      float* __restrict__ out,
                                                      int mb) {
    const int lt   = blockIdx.x;
    const int mloc = blockIdx.y;
    const int m    = mb + mloc;
    const int l0   = lt * 32;
    const int tid  = threadIdx.x;

    if (l0 + 31 < m) {
        int l = l0 + (tid >> 3), bc = tid & 7;
        int idx = (bc * LMAX + l) * MMAX + m;
        if (CPLX) ((float2*)out)[idx] = make_float2(0.f, 0.f);
        else      out[idx] = 0.f;
        return;
    }

    const int kk = tid & 31, lq = tid >> 5;
    const int lb = l0 + lq * 4;

    int lr[4];
#pragma unroll
    for (int j = 0; j < 4; ++j) {
        int l = lb + j;
        if (l < m)        l = m;
        if (l > LMAX - 1) l = LMAX - 1;
        lr[j] = l;
    }

    const float* __restrict__ Wm = W + (size_t)m * (LMAX * NLAT);
    const float4* __restrict__ xt4 = (const float4*)xt;
    constexpr int NX = CPLX ? 4 : 2;
    constexpr int NV = CPLX ? 64 : 32;

    float v[NV];
#pragma unroll
    for (int i = 0; i < NV; ++i) v[i] = 0.f;

#define CLOAD(T, WV, XV) { \
    int kq = (T) * 32 + kk; \
    int kc = (kq < NLAT) ? kq : (NLAT - 1); \
    _Pragma("unroll") \
    for (int j = 0; j < 4; ++j) WV[j] = Wm[lr[j] * NLAT + kc]; \
    int xb = (mloc * NLAT + kc) * NX; \
    _Pragma("unroll") \
    for (int q = 0; q < NX; ++q) XV[q] = xt4[xb + q]; \
    if (kq >= NLAT) { WV[0] = WV[1] = WV[2] = WV[3] = 0.f; } }

#define CFMA(WV, XV) { \
    _Pragma("unroll") \
    for (int j = 0; j < 4; ++j) { \
        float wj = WV[j]; \
        if (CPLX) { \
            _Pragma("unroll") \
            for (int q = 0; q < 4; ++q) { \
                v[j*16 + (2*q  )*2 + 0] += wj * XV[q].x; \
                v[j*16 + (2*q  )*2 + 1] += wj * XV[q].y; \
                v[j*16 + (2*q+1)*2 + 0] += wj * XV[q].z; \
                v[j*16 + (2*q+1)*2 + 1] += wj * XV[q].w; \
            } \
        } else { \
            v[j*8 + 0] += wj * XV[0].x;  v[j*8 + 1] += wj * XV[0].y; \
            v[j*8 + 2] += wj * XV[0].z;  v[j*8 + 3] += wj * XV[0].w; \
            v[j*8 + 4] += wj * XV[1].x;  v[j*8 + 5] += wj * XV[1].y; \
            v[j*8 + 6] += wj * XV[1].z;  v[j*8 + 7] += wj * XV[1].w; \
        } \
    } }

    float  w0[4], w1[4], wn[4];
    float4 x0[NX], x1[NX], xn[NX];
    CLOAD(0, w0, x0)
    CLOAD(1, w1, x1)
#pragma unroll
    for (int t = 0; t < 12; ++t) {
        if (t < 10) CLOAD(t + 2, wn, xn)
        CFMA(w0, x0)
#pragma unroll
        for (int j = 0; j < 4; ++j) w0[j] = w1[j];
#pragma unroll
        for (int q = 0; q < NX; ++q) x0[q] = x1[q];
        if (t < 10) {
#pragma unroll
            for (int j = 0; j < 4; ++j) w1[j] = wn[j];
#pragma unroll
            for (int q = 0; q < NX; ++q) x1[q] = xn[q];
        }
    }
#undef CLOAD
#undef CFMA

#define RSTEP(MASK, CNT) { const bool hi = (kk & MASK) != 0; \
    _Pragma("unroll") \
    for (int i = 0; i < CNT; ++i) { \
        float keep = hi ? v[i + CNT] : v[i]; \
        float send = hi ? v[i] : v[i + CNT]; \
        v[i] = keep + __shfl_xor(send, MASK); } }
    if (CPLX) {
        RSTEP(16, 32) RSTEP(8, 16) RSTEP(4, 8) RSTEP(2, 4) RSTEP(1, 2)
    } else {
        RSTEP(16, 16) RSTEP(8, 8) RSTEP(4, 4) RSTEP(2, 2) RSTEP(1, 1)
    }
#undef RSTEP

    int j  = kk >> 3;
    int bc = kk & 7;
    int l  = l0 + lq * 4 + j;
    if (l >= LMAX) return;
    int idx = (bc * LMAX + l) * MMAX + m;
    if (CPLX) {
        float2 r = make_float2(v[0], v[1]);
        if (l < m) r = make_float2(0.f, 0.f);
        ((float2*)out)[idx] = r;
    } else {
        float r = (l < m) ? 0.f : v[0];
        out[idx] = r;
    }
}

extern "C" void kernel_launch(void* const* d_in, const int* in_sizes, int n_in,
                              void* d_out, int out_size, void* d_ws, size_t ws_size,
                              hipStream_t stream) {
    const float* x = (const float*)d_in[0];
    const float* W = (const float*)d_in[1];
    float* ws = (float*)d_ws;

    const int n_complex = 8 * LMAX * MMAX;            // 1,039,680
    const int cplx = (out_size >= 2 * n_complex) ? 1 : 0;

    if (!cplx) {
        const size_t need = (size_t)(NS + 1) * XTQ_FLOATS * sizeof(float);
        if (ws_size >= need) {
            float* q  = ws;                                    // NS slice buffers
            float* xt = ws + (size_t)NS * XTQ_FLOATS;
            k_dft4<<<dim3(181, NS), dim3(256), 0, stream>>>(x, q, DFT_REP);
            k_reduce6<<<dim3((XTQ_FLOATS / 4 + 255) / 256), dim3(256), 0, stream>>>(
                q, (float4*)xt, RED_REP);
            k_contract4<<<dim3(12, MMAX), dim3(256), 0, stream>>>(W, xt, (float*)d_out,
                                                                  CON_REP);
            return;
        }
    }

    // hedge / fallback: legacy sincosf path (chunked if ws small)
    const int xs_per_mk = cplx ? 16 : 8;
    const size_t per_m_bytes = (size_t)NLAT * xs_per_mk * sizeof(float);
    int CM = (int)(ws_size / per_m_bytes);
    if (CM > MMAX) CM = MMAX;
    if (CM < 1)    CM = 1;
    for (int mbase = 0; mbase < MMAX; mbase += CM) {
        int mc = MMAX - mbase;
        if (mc > CM) mc = CM;
        if (cplx) {
            k_dft_leg<1><<<dim3(NLAT, (mc + 191) / 192), dim3(192), 0, stream>>>(
                x, ws, mbase, mc);
            k_contract_leg<1><<<dim3(12, mc), dim3(256), 0, stream>>>(W, ws, (float*)d_out, mbase);
        } else {
            k_dft_leg<0><<<dim3(NLAT, (mc + 191) / 192), dim3(192), 0, stream>>>(
                x, ws, mbase, mc);
            k_contract_leg<0><<<dim3(12, mc), dim3(256), 0, stream>>>(W, ws, (float*)d_out, mbase);
        }
    }
}

// Round 13
// 59.677 us; speedup vs baseline: 9.5950x; 9.5950x over previous
//
#include <hip/hip_runtime.h>

#define NLAT 361
#define NLON 720
#define LMAX 360
#define MMAX 361

#define XT_FLOATS (MMAX * NLAT * 8)   // 1,042,568 floats (real Xt [m][k][8ch])

static constexpr float kAngF = 8.72664625997164788e-3f;  // 2*pi/720

// ---------------- kernel 1: folded real DFT, m-split, reseeded Chebyshev ----------------
// X[m,k,ch] = (2pi/720) * sum_{n=0}^{360} w_n cos(n*m*th) * (x[n]+x[720-n]),
// w_360 = 1/2 (fixup), n=0 pair = 0. grid (181 kpairs, 3 mchunks), block 256.
__global__ __launch_bounds__(256) void k_dft5(const float* __restrict__ x,
                                              float* __restrict__ xt) {
    const int bx  = blockIdx.x;       // k = 2*bx + ks
    const int mc  = blockIdx.y;       // m chunk
    const int tid = threadIdx.x;
    const int ks  = tid >> 7;         // 0/1
    const int ml  = tid & 127;
    const int m   = mc * 128 + ml;    // 0..383
    const bool mv = (m <= 360);
    const int mm  = mv ? m : 360;

    __shared__ __align__(16) float xe[2][361][12];   // stride 12: b128-aligned

    // fold: xe[s][n][ch] = x[n] + x[720-n]  (n=0 -> no pair)
    for (int j = tid; j < 2 * 8 * 361; j += 256) {
        int s  = j / 2888;
        int r  = j - s * 2888;
        int ch = r / 361;
        int n  = r - ch * 361;
        int k  = bx * 2 + s;
        float v = 0.f;
        if (k <= 360) {
            const float* __restrict__ row = x + ((size_t)ch * NLAT + k) * NLON;
            float a = row[n];
            float b = (n == 0) ? 0.f : row[NLON - n];
            v = a + b;
        }
        xe[s][n][ch] = v;
    }
    __syncthreads();

    float acc[8];
#pragma unroll
    for (int b = 0; b < 8; ++b) acc[b] = 0.f;

    const float c2 = 2.f * __cosf((float)mm * kAngF);

    // 4 reseeded Chebyshev chunks: [0,91) [91,182) [182,273) [273,361)
    const int cb[5] = {0, 91, 182, 273, 361};
#pragma unroll
    for (int c = 0; c < 4; ++c) {
        const int n0 = cb[c], n1 = cb[c + 1];
        int t0 = (n0 * mm) % NLON;                  // exact integer reduction
        int t1 = t0 + mm; if (t1 >= NLON) t1 -= NLON;
        float P0 = __cosf((float)t0 * kAngF);
        float P1 = __cosf((float)t1 * kAngF);
        for (int n = n0; n < n1; ++n) {
            float4 e0 = *(const float4*)&xe[ks][n][0];
            float4 e1 = *(const float4*)&xe[ks][n][4];
            float f = P0;
            acc[0] += f * e0.x;  acc[1] += f * e0.y;
            acc[2] += f * e0.z;  acc[3] += f * e0.w;
            acc[4] += f * e1.x;  acc[5] += f * e1.y;
            acc[6] += f * e1.z;  acc[7] += f * e1.w;
            float Pn = c2 * P1 - P0;
            P0 = P1;
            P1 = Pn;
        }
    }

    {   // n=360 accumulated with weight 1*(-1)^m; correct to weight 0.5
        float4 e0 = *(const float4*)&xe[ks][360][0];
        float4 e1 = *(const float4*)&xe[ks][360][4];
        float h = 0.5f * ((mm & 1) ? -1.f : 1.f);
        acc[0] -= h * e0.x;  acc[1] -= h * e0.y;
        acc[2] -= h * e0.z;  acc[3] -= h * e0.w;
        acc[4] -= h * e1.x;  acc[5] -= h * e1.y;
        acc[6] -= h * e1.z;  acc[7] -= h * e1.w;
    }

#pragma unroll
    for (int b = 0; b < 8; ++b) acc[b] *= kAngF;

    const int k = bx * 2 + ks;
    if (mv && k <= 360) {
        float4* __restrict__ o4 = (float4*)xt;
        int b0 = (m * NLAT + k) * 2;
        o4[b0]     = make_float4(acc[0], acc[1], acc[2], acc[3]);
        o4[b0 + 1] = make_float4(acc[4], acc[5], acc[6], acc[7]);
    }
}

// ---------------- kernel 2: contraction, all-W-upfront registers ----------------
// out[bc,l,m] = sum_k W[m,l,k] * X[m,k]   (zero for l < m), real only.
__global__ __launch_bounds__(256) void k_contract4(const float* __restrict__ W,
                                                   const float* __restrict__ xt,
                                                   float* __restrict__ out) {
    const int lt   = blockIdx.x;
    const int mloc = blockIdx.y;
    const int m    = mloc;
    const int l0   = lt * 32;
    const int tid  = threadIdx.x;

    if (l0 + 31 < m) {
        int l = l0 + (tid >> 3), bc = tid & 7;
        out[(bc * LMAX + l) * MMAX + m] = 0.f;
        return;
    }

    const int kk = tid & 31, lq = tid >> 5;
    const int lb = l0 + lq * 4;

    int lr[4];
#pragma unroll
    for (int j = 0; j < 4; ++j) {
        int l = lb + j;
        if (l < m)        l = m;          // dedup discarded rows onto row m
        if (l > LMAX - 1) l = LMAX - 1;
        lr[j] = l;
    }

    const float* __restrict__ Wm = W + (size_t)m * (LMAX * NLAT);
    const float* __restrict__ r0 = Wm + lr[0] * NLAT + kk;
    const float* __restrict__ r1 = Wm + lr[1] * NLAT + kk;
    const float* __restrict__ r2 = Wm + lr[2] * NLAT + kk;
    const float* __restrict__ r3 = Wm + lr[3] * NLAT + kk;

    float wv[12][4];
#pragma unroll
    for (int t = 0; t < 11; ++t) {
        wv[t][0] = r0[t * 32];
        wv[t][1] = r1[t * 32];
        wv[t][2] = r2[t * 32];
        wv[t][3] = r3[t * 32];
    }
    {
        int kq = 11 * 32 + kk;
        int kc = (kq <= 360) ? kq : 360;
        wv[11][0] = Wm[lr[0] * NLAT + kc];
        wv[11][1] = Wm[lr[1] * NLAT + kc];
        wv[11][2] = Wm[lr[2] * NLAT + kc];
        wv[11][3] = Wm[lr[3] * NLAT + kc];
        if (kq > 360) { wv[11][0] = wv[11][1] = wv[11][2] = wv[11][3] = 0.f; }
    }

    float v[32];
#pragma unroll
    for (int i = 0; i < 32; ++i) v[i] = 0.f;

    const float4* __restrict__ xt4 = (const float4*)xt;
#pragma unroll
    for (int t = 0; t < 12; ++t) {
        int kq = t * 32 + kk;
        int kc = (kq <= 360) ? kq : 360;
        int xb = (mloc * NLAT + kc) * 2;
        float4 x0 = xt4[xb], x1 = xt4[xb + 1];
#pragma unroll
        for (int j = 0; j < 4; ++j) {
            float wj = wv[t][j];
            v[j*8 + 0] += wj * x0.x;  v[j*8 + 1] += wj * x0.y;
            v[j*8 + 2] += wj * x0.z;  v[j*8 + 3] += wj * x0.w;
            v[j*8 + 4] += wj * x1.x;  v[j*8 + 5] += wj * x1.y;
            v[j*8 + 6] += wj * x1.z;  v[j*8 + 7] += wj * x1.w;
        }
    }

#define RSTEP(MASK, CNT) { const bool hi = (kk & MASK) != 0; \
    _Pragma("unroll") \
    for (int i = 0; i < CNT; ++i) { \
        float keep = hi ? v[i + CNT] : v[i]; \
        float send = hi ? v[i] : v[i + CNT]; \
        v[i] = keep + __shfl_xor(send, MASK); } }
    RSTEP(16, 16) RSTEP(8, 8) RSTEP(4, 4) RSTEP(2, 2) RSTEP(1, 1)
#undef RSTEP

    int j  = kk >> 3;
    int bc = kk & 7;
    int l  = l0 + lq * 4 + j;
    if (l >= LMAX) return;
    float r = (l < m) ? 0.f : v[0];
    out[(bc * LMAX + l) * MMAX + m] = r;
}

// ---------------- legacy folded DFT (cplx hedge / small-ws fallback) ----------------
template<int CPLX>
__global__ __launch_bounds__(192) void k_dft_leg(const float* __restrict__ x,
                                                 float* __restrict__ xt,
                                                 int mb, int mc) {
    const int k    = blockIdx.x;
    const int half = blockIdx.y;
    const int tid  = threadIdx.x;

    __shared__ __align__(16) float  xr[8 * 724];
    __shared__ __align__(16) float2 exo[8 * 362];

    {
        const float4* __restrict__ x4 = (const float4*)x;
        for (int j = tid; j < 8 * 180; j += 192) {
            int b = j / 180, q = j - b * 180;
            ((float4*)&xr[b * 724])[q] = x4[(b * NLAT + k) * 180 + q];
        }
        if (tid < 8) ((float4*)&xr[tid * 724])[180] = make_float4(0.f, 0.f, 0.f, 0.f);
    }
    __syncthreads();

    for (int j = tid; j < 8 * NLAT; j += 192) {
        int b = j / NLAT, n = j - b * NLAT;
        float xa  = xr[b * 724 + n];
        float xbv = xr[b * 724 + (NLON - n)];
        exo[b * 362 + n] = make_float2(xa + xbv, xa - xbv);
    }
    __syncthreads();

    const int  m_local = half * 192 + tid;
    const bool valid   = (m_local < mc);
    const int  m       = mb + (valid ? m_local : 0);

    float aRe[8], aIm[8];
#pragma unroll
    for (int b = 0; b < 8; ++b) { aRe[b] = 0.f; aIm[b] = 0.f; }

    int tacc = 0;
    for (int n = 0; n < NLAT; ++n) {
        float sn, cs;
        __sincosf((float)tacc * kAngF, &sn, &cs);
        float wgt = (n == 360) ? 0.5f : 1.0f;
        float fc = wgt * kAngF * cs;
        float fs = -wgt * kAngF * sn;
        tacc += m;
        if (tacc >= NLON) tacc -= NLON;
#pragma unroll
        for (int b = 0; b < 8; ++b) {
            float2 e = exo[b * 362 + n];
            aRe[b] += fc * e.x;
            if (CPLX) aIm[b] += fs * e.y;
        }
    }

    if (valid) {
        float4* __restrict__ xt4 = (float4*)xt;
        if (CPLX) {
            int base = (m_local * NLAT + k) * 4;
#pragma unroll
            for (int q = 0; q < 4; ++q)
                xt4[base + q] = make_float4(aRe[2*q], aIm[2*q], aRe[2*q+1], aIm[2*q+1]);
        } else {
            int base = (m_local * NLAT + k) * 2;
            xt4[base + 0] = make_float4(aRe[0], aRe[1], aRe[2], aRe[3]);
            xt4[base + 1] = make_float4(aRe[4], aRe[5], aRe[6], aRe[7]);
        }
    }
}

// ---------------- legacy contraction (fallback only) ----------------
template<int CPLX>
__global__ __launch_bounds__(256) void k_contract_leg(const float* __restrict__ W,
                                                      const float* __restrict__ xt,
                                                      float* __restrict__ out,
                                                      int mb) {
    const int lt   = blockIdx.x;
    const int mloc = blockIdx.y;
    const int m    = mb + mloc;
    const int l0   = lt * 32;
    const int tid  = threadIdx.x;

    if (l0 + 31 < m) {
        int l = l0 + (tid >> 3), bc = tid & 7;
        int idx = (bc * LMAX + l) * MMAX + m;
        if (CPLX) ((float2*)out)[idx] = make_float2(0.f, 0.f);
        else      out[idx] = 0.f;
        return;
    }

    const int kk = tid & 31, lq = tid >> 5;
    const int lb = l0 + lq * 4;

    int lr[4];
#pragma unroll
    for (int j = 0; j < 4; ++j) {
        int l = lb + j;
        if (l < m)        l = m;
        if (l > LMAX - 1) l = LMAX - 1;
        lr[j] = l;
    }

    const float* __restrict__ Wm = W + (size_t)m * (LMAX * NLAT);
    const float4* __restrict__ xt4 = (const float4*)xt;
    constexpr int NX = CPLX ? 4 : 2;
    constexpr int NV = CPLX ? 64 : 32;

    float v[NV];
#pragma unroll
    for (int i = 0; i < NV; ++i) v[i] = 0.f;

#define CLOAD(T, WV, XV) { \
    int kq = (T) * 32 + kk; \
    int kc = (kq < NLAT) ? kq : (NLAT - 1); \
    _Pragma("unroll") \
    for (int j = 0; j < 4; ++j) WV[j] = Wm[lr[j] * NLAT + kc]; \
    int xb = (mloc * NLAT + kc) * NX; \
    _Pragma("unroll") \
    for (int q = 0; q < NX; ++q) XV[q] = xt4[xb + q]; \
    if (kq >= NLAT) { WV[0] = WV[1] = WV[2] = WV[3] = 0.f; } }

#define CFMA(WV, XV) { \
    _Pragma("unroll") \
    for (int j = 0; j < 4; ++j) { \
        float wj = WV[j]; \
        if (CPLX) { \
            _Pragma("unroll") \
            for (int q = 0; q < 4; ++q) { \
                v[j*16 + (2*q  )*2 + 0] += wj * XV[q].x; \
                v[j*16 + (2*q  )*2 + 1] += wj * XV[q].y; \
                v[j*16 + (2*q+1)*2 + 0] += wj * XV[q].z; \
                v[j*16 + (2*q+1)*2 + 1] += wj * XV[q].w; \
            } \
        } else { \
            v[j*8 + 0] += wj * XV[0].x;  v[j*8 + 1] += wj * XV[0].y; \
            v[j*8 + 2] += wj * XV[0].z;  v[j*8 + 3] += wj * XV[0].w; \
            v[j*8 + 4] += wj * XV[1].x;  v[j*8 + 5] += wj * XV[1].y; \
            v[j*8 + 6] += wj * XV[1].z;  v[j*8 + 7] += wj * XV[1].w; \
        } \
    } }

    float  w0[4], w1[4], wn[4];
    float4 x0[NX], x1[NX], xn[NX];
    CLOAD(0, w0, x0)
    CLOAD(1, w1, x1)
#pragma unroll
    for (int t = 0; t < 12; ++t) {
        if (t < 10) CLOAD(t + 2, wn, xn)
        CFMA(w0, x0)
#pragma unroll
        for (int j = 0; j < 4; ++j) w0[j] = w1[j];
#pragma unroll
        for (int q = 0; q < NX; ++q) x0[q] = x1[q];
        if (t < 10) {
#pragma unroll
            for (int j = 0; j < 4; ++j) w1[j] = wn[j];
#pragma unroll
            for (int q = 0; q < NX; ++q) x1[q] = xn[q];
        }
    }
#undef CLOAD
#undef CFMA

#define RSTEP(MASK, CNT) { const bool hi = (kk & MASK) != 0; \
    _Pragma("unroll") \
    for (int i = 0; i < CNT; ++i) { \
        float keep = hi ? v[i + CNT] : v[i]; \
        float send = hi ? v[i] : v[i + CNT]; \
        v[i] = keep + __shfl_xor(send, MASK); } }
    if (CPLX) {
        RSTEP(16, 32) RSTEP(8, 16) RSTEP(4, 8) RSTEP(2, 4) RSTEP(1, 2)
    } else {
        RSTEP(16, 16) RSTEP(8, 8) RSTEP(4, 4) RSTEP(2, 2) RSTEP(1, 1)
    }
#undef RSTEP

    int j  = kk >> 3;
    int bc = kk & 7;
    int l  = l0 + lq * 4 + j;
    if (l >= LMAX) return;
    int idx = (bc * LMAX + l) * MMAX + m;
    if (CPLX) {
        float2 r = make_float2(v[0], v[1]);
        if (l < m) r = make_float2(0.f, 0.f);
        ((float2*)out)[idx] = r;
    } else {
        float r = (l < m) ? 0.f : v[0];
        out[idx] = r;
    }
}

extern "C" void kernel_launch(void* const* d_in, const int* in_sizes, int n_in,
                              void* d_out, int out_size, void* d_ws, size_t ws_size,
                              hipStream_t stream) {
    const float* x = (const float*)d_in[0];
    const float* W = (const float*)d_in[1];
    float* ws = (float*)d_ws;

    const int n_complex = 8 * LMAX * MMAX;            // 1,039,680
    const int cplx = (out_size >= 2 * n_complex) ? 1 : 0;

    if (!cplx && ws_size >= (size_t)XT_FLOATS * sizeof(float)) {
        k_dft5<<<dim3(181, 3), dim3(256), 0, stream>>>(x, ws);
        k_contract4<<<dim3(12, MMAX), dim3(256), 0, stream>>>(W, ws, (float*)d_out);
        return;
    }

    // hedge / fallback: legacy sincosf path (chunked if ws small)
    const int xs_per_mk = cplx ? 16 : 8;
    const size_t per_m_bytes = (size_t)NLAT * xs_per_mk * sizeof(float);
    int CM = (int)(ws_size / per_m_bytes);
    if (CM > MMAX) CM = MMAX;
    if (CM < 1)    CM = 1;
    for (int mbase = 0; mbase < MMAX; mbase += CM) {
        int mc = MMAX - mbase;
        if (mc > CM) mc = CM;
        if (cplx) {
            k_dft_leg<1><<<dim3(NLAT, (mc + 191) / 192), dim3(192), 0, stream>>>(
                x, ws, mbase, mc);
            k_contract_leg<1><<<dim3(12, mc), dim3(256), 0, stream>>>(W, ws, (float*)d_out, mbase);
        } else {
            k_dft_leg<0><<<dim3(NLAT, (mc + 191) / 192), dim3(192), 0, stream>>>(
                x, ws, mbase, mc);
            k_contract_leg<0><<<dim3(12, mc), dim3(256), 0, stream>>>(W, ws, (float*)d_out, mbase);
        }
    }
}